// Round 5
// baseline (2151.484 us; speedup 1.0000x reference)
//
#include <hip/hip_runtime.h>

#define B_ 64
#define T_ 256
#define E_ 256
#define H_ 256
#define G4 1024   // 4*H
#define L_ 9

typedef __attribute__((ext_vector_type(8))) short bf16x8;
typedef __attribute__((ext_vector_type(4))) float f32x4;
typedef _Float16 half2v __attribute__((ext_vector_type(2)));

__device__ __forceinline__ ushort f2bf(float x){
  unsigned u = __float_as_uint(x);
  unsigned r = (u + 0x7FFFu + ((u >> 16) & 1u)) >> 16;
  return (ushort)r;
}
__device__ __forceinline__ float bf2f(unsigned u16v){
  return __uint_as_float(u16v << 16);
}
__device__ __forceinline__ float fsig(float x){
  return __builtin_amdgcn_rcpf(1.f + __expf(-x));
}
__device__ __forceinline__ float ftanh(float x){
  return 1.f - 2.f * __builtin_amdgcn_rcpf(__expf(2.f * x) + 1.f);
}

// ===== fused prep: WT | UT | gather | seqlen =====
__global__ void k_prep(const int* __restrict__ inp, const float* __restrict__ emb,
                       const float* __restrict__ Wf, const float* __restrict__ Wb,
                       const float* __restrict__ Uf, const float* __restrict__ Ub,
                       ushort* __restrict__ WT, ushort* __restrict__ UT,
                       ushort* __restrict__ X, int* __restrict__ lens,
                       float* __restrict__ out_len){
  int bid = blockIdx.x, tid = threadIdx.x;
  if (bid < 2048){                                   // W -> bf16 transposed [dir][n][k]
    int idx = bid * 256 + tid;
    int dir = idx >> 18; int rem = idx & 262143;
    int n = rem >> 8, k = rem & 255;
    const float* W = dir ? Wb : Wf;
    WT[idx] = f2bf(W[k * G4 + n]);
  } else if (bid < 4096){                            // U -> bf16 transposed [dir][C][k]
    int idx = (bid - 2048) * 256 + tid;
    int dir = idx >> 18; int rem = idx & 262143;
    int C = rem >> 8, k = rem & 255;
    const float* U = dir ? Ub : Uf;
    UT[idx] = f2bf(U[k * G4 + C]);
  } else if (bid < 6144){                            // X = bf16(emb[inp])
    int idx = (bid - 4096) * 256 + tid;
    int m = idx >> 5, koff = (idx & 31) * 8;
    int tok = inp[m];
    const float* src = emb + (size_t)tok * E_ + koff;
    float4 a = *(const float4*)src;
    float4 b = *(const float4*)(src + 4);
    uint4 o;
    o.x = (unsigned)f2bf(a.x) | ((unsigned)f2bf(a.y) << 16);
    o.y = (unsigned)f2bf(a.z) | ((unsigned)f2bf(a.w) << 16);
    o.z = (unsigned)f2bf(b.x) | ((unsigned)f2bf(b.y) << 16);
    o.w = (unsigned)f2bf(b.z) | ((unsigned)f2bf(b.w) << 16);
    *(uint4*)(X + m * E_ + koff) = o;
  } else {                                           // seq_lens: 16 blocks x 4 waves
    int w = tid >> 6, lane = tid & 63;
    int b = (bid - 6144) * 4 + w;
    int c = 0;
    for (int t = lane; t < T_; t += 64) c += (inp[b * T_ + t] != 0);
    for (int off = 32; off; off >>= 1) c += __shfl_xor(c, off);
    if (lane == 0){ lens[b] = c; out_len[b] = (float)c; }
  }
}

// ===== Z = X @ W + bias (bf16 MFMA) -> packed bf16 [tok][j<256][gate<4] =====
__global__ __launch_bounds__(256) void k_gemm(const ushort* __restrict__ X,
        const ushort* __restrict__ WT, const float* __restrict__ bf_,
        const float* __restrict__ bb_, ushort* __restrict__ Zpf, ushort* __restrict__ Zpb){
  int zi = blockIdx.z;
  const ushort* wt = WT + zi * 262144;
  const float* bias = zi ? bb_ : bf_;
  ushort* Zp = zi ? Zpb : Zpf;
  int m0 = blockIdx.x * 128, n0 = blockIdx.y * 128;
  __shared__ ushort As[128][40];
  __shared__ ushort Bs[128][40];
  int tid = threadIdx.x;
  int sr = tid >> 1, sk = (tid & 1) * 16;
  const ushort* xg = X + (m0 + sr) * E_ + sk;
  const ushort* wg = wt + (n0 + sr) * E_ + sk;
  f32x4 acc[4][4] = {};
  int lane = tid & 63, wv = tid >> 6;
  int wr = wv >> 1, wc = wv & 1;
  int lrow = lane & 15, kf = (lane >> 4) * 8;
  for (int k0 = 0; k0 < E_; k0 += 32){
    uint4 a0 = *(const uint4*)(xg + k0);
    uint4 a1 = *(const uint4*)(xg + k0 + 8);
    uint4 b0 = *(const uint4*)(wg + k0);
    uint4 b1 = *(const uint4*)(wg + k0 + 8);
    *(uint4*)&As[sr][sk]     = a0;  *(uint4*)&As[sr][sk + 8] = a1;
    *(uint4*)&Bs[sr][sk]     = b0;  *(uint4*)&Bs[sr][sk + 8] = b1;
    __syncthreads();
    bf16x8 af[4], bfr[4];
    #pragma unroll
    for (int i = 0; i < 4; i++) af[i]  = *(const bf16x8*)&As[wr * 64 + i * 16 + lrow][kf];
    #pragma unroll
    for (int i = 0; i < 4; i++) bfr[i] = *(const bf16x8*)&Bs[wc * 64 + i * 16 + lrow][kf];
    #pragma unroll
    for (int i = 0; i < 4; i++)
      #pragma unroll
      for (int j = 0; j < 4; j++)
        acc[i][j] = __builtin_amdgcn_mfma_f32_16x16x32_bf16(af[i], bfr[j], acc[i][j], 0, 0, 0);
    __syncthreads();
  }
  int crow = (lane >> 4) * 4;
  #pragma unroll
  for (int j = 0; j < 4; j++){
    int col = n0 + wc * 64 + j * 16 + lrow;
    float bv = bias[col];
    int gg = col >> 8, jj = col & 255;
    #pragma unroll
    for (int i = 0; i < 4; i++){
      int rbase = m0 + wr * 64 + i * 16 + crow;
      #pragma unroll
      for (int r = 0; r < 4; r++)
        Zp[((size_t)(rbase + r) * 256 + jj) * 4 + gg] = f2bf(acc[i][j][r] + bv);
    }
  }
}

// ===== LSTM recurrence v5: WG-private, full U on-CU (regs+LDS), no inter-WG traffic =====
// 16 WGs x 256 thr (4 waves, 1 wave/SIMD, up to 512 VGPR).
// bid: dir = bid&1, grp = bid>>1 (8 batches each). Wave w owns N-tiles {w*4+q+16*g2}.
// g2<3 tiles in VGPRs (12), g2==3 tiles in LDS fragment-order (4).
__global__ __launch_bounds__(256, 1) void k_recur5(
    const ushort* __restrict__ Zpf, const ushort* __restrict__ Zpb,
    const ushort* __restrict__ UT, const int* __restrict__ lens,
    ushort* __restrict__ hf16, ushort* __restrict__ hb16){
  int bid = blockIdx.x;
  int dir = bid & 1, grp = bid >> 1;
  int b0 = grp * 8;
  const uint2* Zp2 = (const uint2*)(dir ? Zpb : Zpf);
  ushort* H = dir ? hb16 : hf16;
  const ushort* Ud = UT + dir * 262144;

  int tid = threadIdx.x;
  int lane = tid & 63, w = tid >> 6;
  int l15 = lane & 15, lq = lane >> 4;
  int rr = l15 & 7;                       // A row (M=8, rows 8-15 duplicate)

  __shared__ ushort Blds[16][8][64][8];   // 128 KB, fragment order
  __shared__ ushort hsh[2][8][264];       // 8.25 KB, XOR-swizzled k-groups

  // ---- load B fragments: 12 reg tiles ----
  bf16x8 Breg[96];                        // [(q*3+g2)*8+kb]
  #pragma unroll
  for (int q = 0; q < 4; q++)
    #pragma unroll
    for (int g2 = 0; g2 < 3; g2++){
      int C = (w * 4 + q) * 16 + g2 * 256 + l15;
      const ushort* bp = Ud + C * 256 + lq * 8;
      #pragma unroll
      for (int kb = 0; kb < 8; kb++){
        Breg[(q * 3 + g2) * 8 + kb] = *(const bf16x8*)(bp + kb * 32);
        asm volatile("" : "+v"(Breg[(q * 3 + g2) * 8 + kb]));   // keep in VGPRs
      }
    }
  // ---- 4 LDS tiles (g2==3) ----
  #pragma unroll
  for (int q = 0; q < 4; q++){
    int C = (w * 4 + q) * 16 + 3 * 256 + l15;
    const ushort* bp = Ud + C * 256 + lq * 8;
    #pragma unroll
    for (int kb = 0; kb < 8; kb++)
      *(uint4*)&Blds[w * 4 + q][kb][lane][0] = *(const uint4*)(bp + kb * 32);
  }
  __syncthreads();

  int lenr[4];
  #pragma unroll
  for (int r = 0; r < 4; r++) lenr[r] = lens[b0 + (lq & 1) * 4 + r];

  float cst[16];                          // [q*4+r]
  unsigned hst[8];                        // packed bf16 pairs [q*2 + r/2]
  #pragma unroll
  for (int i = 0; i < 16; i++) cst[i] = 0.f;
  #pragma unroll
  for (int i = 0; i < 8; i++) hst[i] = 0u;

  uint2 zpre[4][4];                       // [quarter][r], issued 1 step ahead
  int jcol = l15;                         // + (w*4+q)*16

#define ZISSUE(QQ, TQ) if (lq < 2){ \
    int jq = (w * 4 + (QQ)) * 16 + jcol; \
    _Pragma("unroll") \
    for (int r = 0; r < 4; r++) \
      zpre[QQ][r] = Zp2[((size_t)(b0 + lq * 4 + r) * 256 + (TQ)) * 256 + jq]; }

  {
    int t0 = dir ? 255 : 0;
    ZISSUE(0, t0) ZISSUE(1, t0) ZISSUE(2, t0) ZISSUE(3, t0)
  }

#define QUARTER(QQ) { \
    f32x4 aq[4] = {}; \
    if (s_ > 0){ \
      _Pragma("unroll") \
      for (int kb = 0; kb < 8; kb++){ \
        bf16x8 af = *(const bf16x8*)&hsh[cur][rr][((kb * 4 + lq) ^ rr) << 3]; \
        aq[0] = __builtin_amdgcn_mfma_f32_16x16x32_bf16(af, Breg[((QQ)*3+0)*8+kb], aq[0], 0,0,0); \
        aq[1] = __builtin_amdgcn_mfma_f32_16x16x32_bf16(af, Breg[((QQ)*3+1)*8+kb], aq[1], 0,0,0); \
        aq[2] = __builtin_amdgcn_mfma_f32_16x16x32_bf16(af, Breg[((QQ)*3+2)*8+kb], aq[2], 0,0,0); \
        bf16x8 bl = *(const bf16x8*)&Blds[w * 4 + (QQ)][kb][lane][0]; \
        aq[3] = __builtin_amdgcn_mfma_f32_16x16x32_bf16(af, bl, aq[3], 0,0,0); \
      } \
    } \
    if (lq < 2){ \
      _Pragma("unroll") \
      for (int r = 0; r < 4; r++){ \
        uint2 zw = zpre[QQ][r]; \
        float zi = bf2f(zw.x & 0xffffu) + aq[0][r]; \
        float zf = bf2f(zw.x >> 16)     + aq[1][r]; \
        float zg = bf2f(zw.y & 0xffffu) + aq[2][r]; \
        float zo = bf2f(zw.y >> 16)     + aq[3][r]; \
        int ci = (QQ) * 4 + r, wi = (QQ) * 2 + (r >> 1), sh = (r & 1) * 16; \
        unsigned nb = (hst[wi] >> sh) & 0xffffu; \
        if (t < lenr[r]){ \
          float cn = fsig(zf) * cst[ci] + fsig(zi) * ftanh(zg); \
          cst[ci] = cn; \
          nb = f2bf(fsig(zo) * ftanh(cn)); \
        } \
        hst[wi] = (hst[wi] & ~(0xffffu << sh)) | (nb << sh); \
        unsigned ob = (unsigned)__shfl_xor((int)nb, 1); \
        if (!(l15 & 1)){ \
          unsigned word = nb | (ob << 16); \
          int m = lq * 4 + r; \
          int j = (w * 4 + (QQ)) * 16 + l15; \
          int g8 = (j >> 3) ^ m; \
          *(unsigned*)&hsh[nxt][m][(g8 << 3) | (j & 7)] = word; \
          *(unsigned*)&H[((size_t)(b0 + m) * 256 + t) * 256 + j] = word; \
        } \
      } \
      if (s_ < 255){ ZISSUE(QQ, tn) } \
    } \
  }

  for (int s_ = 0; s_ < 256; ++s_){
    int t = dir ? (255 - s_) : s_;
    int tn = dir ? (t - 1) : (t + 1);
    int cur = s_ & 1, nxt = cur ^ 1;
    QUARTER(0)
    QUARTER(1)
    QUARTER(2)
    QUARTER(3)
    __syncthreads();
  }
#undef QUARTER
#undef ZISSUE
}

// ===== pot = [hf|hb] @ Wd + bd (one wave per row, bf16 h) =====
__global__ __launch_bounds__(256) void k_pot(const ushort* __restrict__ hf16,
        const ushort* __restrict__ hb16, const float* __restrict__ Wd,
        const float* __restrict__ bd, float* __restrict__ out, int* __restrict__ cnt){
  if (blockIdx.x == 0 && threadIdx.x == 0) *cnt = 0;
  int lane = threadIdx.x & 63, wid = threadIdx.x >> 6;
  int m = blockIdx.x * 4 + wid;
  uint2 ua = *(const uint2*)&hf16[(size_t)m * H_ + lane * 4];
  uint2 ub = *(const uint2*)&hb16[(size_t)m * H_ + lane * 4];
  float av[4] = {bf2f(ua.x & 0xFFFFu), bf2f(ua.x >> 16), bf2f(ua.y & 0xFFFFu), bf2f(ua.y >> 16)};
  float bv[4] = {bf2f(ub.x & 0xFFFFu), bf2f(ub.x >> 16), bf2f(ub.y & 0xFFFFu), bf2f(ub.y >> 16)};
  float acc[9];
  #pragma unroll
  for (int l = 0; l < 9; l++) acc[l] = 0.f;
  #pragma unroll
  for (int i = 0; i < 4; i++){
    int r = lane * 4 + i;
    #pragma unroll
    for (int l = 0; l < 9; l++)
      acc[l] += av[i] * Wd[r * 9 + l] + bv[i] * Wd[(H_ + r) * 9 + l];
  }
  #pragma unroll
  for (int off = 32; off; off >>= 1)
    #pragma unroll
    for (int l = 0; l < 9; l++) acc[l] += __shfl_xor(acc[l], off);
  if (lane == 0){
    #pragma unroll
    for (int l = 0; l < 9; l++) out[(size_t)m * 9 + l] = acc[l] + bd[l];
  }
}

// ===== CRF log-likelihood + loss (fused, last-block reduce) =====
__global__ void k_post(const float* __restrict__ out, const int* __restrict__ tags,
                       const float* __restrict__ trans, const int* __restrict__ lens,
                       float* __restrict__ lln, int* cnt, float* __restrict__ loss_out){
  int b = blockIdx.x, lane = threadIdx.x;
  int len = lens[b];
  const float* pot = out + (size_t)b * T_ * 9;
  float up = 0.f, bp = 0.f;
  for (int t = lane; t < T_; t += 64){
    int tg = tags[b * T_ + t];
    if (t < len) up += pot[t * 9 + tg];
    if (t + 1 < len){
      int tg2 = tags[b * T_ + t + 1];
      bp += trans[tg * 9 + tg2];
    }
  }
  for (int off = 32; off; off >>= 1){ up += __shfl_xor(up, off); bp += __shfl_xor(bp, off); }
  float alpha = 0.f;
  if (lane < 9){
    float tr[9];
    #pragma unroll
    for (int i = 0; i < 9; i++) tr[i] = trans[i * 9 + lane];
    alpha = pot[lane];
    for (int t = 1; t < T_; ++t){
      float v[9];
      #pragma unroll
      for (int i = 0; i < 9; i++) v[i] = __shfl(alpha, i) + tr[i];
      float mx = v[0];
      #pragma unroll
      for (int i = 1; i < 9; i++) mx = fmaxf(mx, v[i]);
      float sum = 0.f;
      #pragma unroll
      for (int i = 0; i < 9; i++) sum += __expf(v[i] - mx);
      float an = pot[t * 9 + lane] + mx + __logf(sum);
      if (t < len) alpha = an;
    }
  }
  float mx2 = -3.4e38f;
  for (int i = 0; i < 9; i++){ float a = __shfl(alpha, i); mx2 = fmaxf(mx2, a); }
  float s2 = 0.f;
  for (int i = 0; i < 9; i++){ float a = __shfl(alpha, i); s2 += __expf(a - mx2); }
  float lse = mx2 + __logf(s2);
  __shared__ int lastf;
  if (lane == 0){
    __hip_atomic_store(&lln[b], (up + bp - lse) / (float)len,
                       __ATOMIC_RELAXED, __HIP_MEMORY_SCOPE_AGENT);
    int old = __hip_atomic_fetch_add(cnt, 1, __ATOMIC_ACQ_REL, __HIP_MEMORY_SCOPE_AGENT);
    lastf = (old == 63);
  }
  __syncthreads();
  if (lastf){
    float v = __hip_atomic_load(&lln[lane], __ATOMIC_RELAXED, __HIP_MEMORY_SCOPE_AGENT);
    for (int off = 32; off; off >>= 1) v += __shfl_xor(v, off);
    if (lane == 0) loss_out[0] = -v * (1.f / 64.f);
  }
}

extern "C" void kernel_launch(void* const* d_in, const int* in_sizes, int n_in,
                              void* d_out, int out_size, void* d_ws, size_t ws_size,
                              hipStream_t stream) {
  (void)in_sizes; (void)n_in; (void)out_size; (void)ws_size;
  const int*   inp   = (const int*)  d_in[0];
  const int*   tags  = (const int*)  d_in[1];
  const float* emb   = (const float*)d_in[2];
  const float* Wf    = (const float*)d_in[3];
  const float* Uf    = (const float*)d_in[4];
  const float* bfv   = (const float*)d_in[5];
  const float* Wb    = (const float*)d_in[6];
  const float* Ub    = (const float*)d_in[7];
  const float* bbv   = (const float*)d_in[8];
  const float* Wd    = (const float*)d_in[9];
  const float* bd    = (const float*)d_in[10];
  const float* trans = (const float*)d_in[11];
  float* out = (float*)d_out;

  char* ws = (char*)d_ws;
  ushort* UT16 = (ushort*)(ws);                  // 1 MB
  ushort* WT16 = (ushort*)(ws + 1048576);        // 1 MB
  ushort* Xbf  = (ushort*)(ws + 2097152);        // 8 MB
  int*    cnt  = (int*)   (ws + 2097152);        // aliases Xbf (dead by k_pot)
  ushort* Zpf  = (ushort*)(ws + 10485760);       // 32 MB packed bf16 [tok][j][g]
  ushort* Zpb  = (ushort*)(ws + 44040192);       // 32 MB
  ushort* hf16 = (ushort*)(ws + 77594624);       // 8 MB
  ushort* hb16 = (ushort*)(ws + 85983232);       // 8 MB
  int*    lens = (int*)   (ws + 94371840);       // 256 B
  float*  lln  = (float*) (ws + 94372096);       // 256 B

  k_prep<<<6160, 256, 0, stream>>>(inp, emb, Wf, Wb, Uf, Ub, WT16, UT16, Xbf,
                                   lens, out + 147456);
  k_gemm<<<dim3(128, 8, 2), 256, 0, stream>>>(Xbf, WT16, bfv, bbv, Zpf, Zpb);
  k_recur5<<<16, 256, 0, stream>>>(Zpf, Zpb, UT16, lens, hf16, hb16);
  k_pot<<<4096, 256, 0, stream>>>(hf16, hb16, Wd, bd, out, cnt);
  k_post<<<64, 64, 0, stream>>>(out, tags, trans, lens, lln, cnt, out + 147520);
}

// Round 6
// 602.190 us; speedup vs baseline: 3.5728x; 3.5728x over previous
//
#include <hip/hip_runtime.h>

#define B_ 64
#define T_ 256
#define E_ 256
#define H_ 256
#define G4 1024   // 4*H
#define L_ 9
#define SENT 0xFFFFFFFFu

typedef __attribute__((ext_vector_type(8))) short bf16x8;
typedef __attribute__((ext_vector_type(4))) float f32x4;
typedef _Float16 half2v __attribute__((ext_vector_type(2)));

__device__ __forceinline__ ushort f2bf(float x){
  unsigned u = __float_as_uint(x);
  unsigned r = (u + 0x7FFFu + ((u >> 16) & 1u)) >> 16;
  return (ushort)r;
}
__device__ __forceinline__ ushort f2h(float x){
  _Float16 h = (_Float16)x;
  return __builtin_bit_cast(ushort, h);
}
__device__ __forceinline__ float h2lo(unsigned w){
  return (float)__builtin_bit_cast(half2v, w)[0];
}
__device__ __forceinline__ float h2hi(unsigned w){
  return (float)__builtin_bit_cast(half2v, w)[1];
}
__device__ __forceinline__ float bf2f(unsigned u16v){
  return __uint_as_float(u16v << 16);
}
__device__ __forceinline__ float fdot2(unsigned a, unsigned b, float c){
  return __builtin_amdgcn_fdot2(__builtin_bit_cast(half2v, a),
                                __builtin_bit_cast(half2v, b), c, false);
}
__device__ __forceinline__ float fsig(float x){
  return __builtin_amdgcn_rcpf(1.f + __expf(-x));
}
__device__ __forceinline__ float ftanh(float x){
  return 1.f - 2.f * __builtin_amdgcn_rcpf(__expf(2.f * x) + 1.f);
}

// ===== fused prep: WT | Upk2 | gather | hbuf-init | seqlen =====
__global__ void k_prep(const int* __restrict__ inp, const float* __restrict__ emb,
                       const float* __restrict__ Wf, const float* __restrict__ Wb,
                       const float* __restrict__ Uf, const float* __restrict__ Ub,
                       ushort* __restrict__ WT, unsigned* __restrict__ Upk2,
                       ushort* __restrict__ X, int* __restrict__ lens,
                       float* __restrict__ out_len, uint4* __restrict__ hbuf4){
  int bid = blockIdx.x, tid = threadIdx.x;
  if (bid < 2048){                                   // W -> bf16 transposed [dir][n][k]
    int idx = bid * 256 + tid;
    int dir = idx >> 18; int rem = idx & 262143;
    int n = rem >> 8, k = rem & 255;
    const float* W = dir ? Wb : Wf;
    WT[idx] = f2bf(W[k * G4 + n]);
  } else if (bid < 3072){                            // U -> f16 pairs [dir][gcol<1024][p<128]
    int idx = (bid - 2048) * 256 + tid;
    int dir = idx >> 17; int rem = idx & 131071;
    int gcol = rem >> 7, p = rem & 127;
    const float* U = dir ? Ub : Uf;
    unsigned lo = f2h(U[(2 * p) * G4 + gcol]);
    unsigned hi = f2h(U[(2 * p + 1) * G4 + gcol]);
    Upk2[idx] = lo | (hi << 16);
  } else if (bid < 5120){                            // X = bf16(emb[inp])
    int idx = (bid - 3072) * 256 + tid;
    int m = idx >> 5, koff = (idx & 31) * 8;
    int tok = inp[m];
    const float* src = emb + (size_t)tok * E_ + koff;
    float4 a = *(const float4*)src;
    float4 b = *(const float4*)(src + 4);
    uint4 o;
    o.x = (unsigned)f2bf(a.x) | ((unsigned)f2bf(a.y) << 16);
    o.y = (unsigned)f2bf(a.z) | ((unsigned)f2bf(a.w) << 16);
    o.z = (unsigned)f2bf(b.x) | ((unsigned)f2bf(b.y) << 16);
    o.w = (unsigned)f2bf(b.z) | ((unsigned)f2bf(b.w) << 16);
    *(uint4*)(X + m * E_ + koff) = o;
  } else if (bid < 9216){                            // hbuf = SENT (16 MB)
    int i = (bid - 5120) * 256 + tid;
    hbuf4[i] = uint4{SENT, SENT, SENT, SENT};
  } else {                                           // seq_lens: 16 blocks x 4 waves
    int w = tid >> 6, lane = tid & 63;
    int b = (bid - 9216) * 4 + w;
    int c = 0;
    for (int t = lane; t < T_; t += 64) c += (inp[b * T_ + t] != 0);
    for (int off = 32; off; off >>= 1) c += __shfl_xor(c, off);
    if (lane == 0){ lens[b] = c; out_len[b] = (float)c; }
  }
}

// ===== Z = X @ W + bias (bf16 MFMA) -> packed bf16 [tok][j<256][gate<4] =====
__global__ __launch_bounds__(256) void k_gemm(const ushort* __restrict__ X,
        const ushort* __restrict__ WT, const float* __restrict__ bf_,
        const float* __restrict__ bb_, ushort* __restrict__ Zpf, ushort* __restrict__ Zpb){
  int zi = blockIdx.z;
  const ushort* wt = WT + zi * 262144;
  const float* bias = zi ? bb_ : bf_;
  ushort* Zp = zi ? Zpb : Zpf;
  int m0 = blockIdx.x * 128, n0 = blockIdx.y * 128;
  __shared__ ushort As[128][40];
  __shared__ ushort Bs[128][40];
  int tid = threadIdx.x;
  int sr = tid >> 1, sk = (tid & 1) * 16;
  const ushort* xg = X + (m0 + sr) * E_ + sk;
  const ushort* wg = wt + (n0 + sr) * E_ + sk;
  f32x4 acc[4][4] = {};
  int lane = tid & 63, wv = tid >> 6;
  int wr = wv >> 1, wc = wv & 1;
  int lrow = lane & 15, kf = (lane >> 4) * 8;
  for (int k0 = 0; k0 < E_; k0 += 32){
    uint4 a0 = *(const uint4*)(xg + k0);
    uint4 a1 = *(const uint4*)(xg + k0 + 8);
    uint4 b0 = *(const uint4*)(wg + k0);
    uint4 b1 = *(const uint4*)(wg + k0 + 8);
    *(uint4*)&As[sr][sk]     = a0;  *(uint4*)&As[sr][sk + 8] = a1;
    *(uint4*)&Bs[sr][sk]     = b0;  *(uint4*)&Bs[sr][sk + 8] = b1;
    __syncthreads();
    bf16x8 af[4], bfr[4];
    #pragma unroll
    for (int i = 0; i < 4; i++) af[i]  = *(const bf16x8*)&As[wr * 64 + i * 16 + lrow][kf];
    #pragma unroll
    for (int i = 0; i < 4; i++) bfr[i] = *(const bf16x8*)&Bs[wc * 64 + i * 16 + lrow][kf];
    #pragma unroll
    for (int i = 0; i < 4; i++)
      #pragma unroll
      for (int j = 0; j < 4; j++)
        acc[i][j] = __builtin_amdgcn_mfma_f32_16x16x32_bf16(af[i], bfr[j], acc[i][j], 0, 0, 0);
    __syncthreads();
  }
  int crow = (lane >> 4) * 4;
  #pragma unroll
  for (int j = 0; j < 4; j++){
    int col = n0 + wc * 64 + j * 16 + lrow;
    float bv = bias[col];
    int gg = col >> 8, jj = col & 255;
    #pragma unroll
    for (int i = 0; i < 4; i++){
      int rbase = m0 + wr * 64 + i * 16 + crow;
      #pragma unroll
      for (int r = 0; r < 4; r++)
        Zp[((size_t)(rbase + r) * 256 + jj) * 4 + gg] = f2bf(acc[i][j][r] + bv);
    }
  }
}

// ===== LSTM recurrence v6: R2 structure + pinned-U-in-regs + packed-Z =====
// grid 256: bid = s*64 + g, g = dir*32+bg. Peers 64 apart (same XCD, round-robin).
// 512 threads, 2 batches per WG. hg per group: [t][ab<2][p<128] unsigned f16-pair.
__global__ __launch_bounds__(512, 2) void k_recur6(
    const ushort* __restrict__ Zpf, const ushort* __restrict__ Zpb,
    const unsigned* __restrict__ Upk2, const int* __restrict__ lens,
    ushort* __restrict__ hf16, ushort* __restrict__ hb16,
    unsigned* hbuf){
  int bid = blockIdx.x;
  int g = bid & 63, s = bid >> 6;
  int dir = g >> 5, bg = g & 31;
  int b0 = bg * 2;
  const uint2* Zp = (const uint2*)(dir ? Zpb : Zpf);
  ushort* H = dir ? hb16 : hf16;
  const unsigned* U = Upk2 + dir * 131072;
  unsigned* hg = hbuf + g * 65536;

  int tid = threadIdx.x;
  int lane = tid & 63, wv = tid >> 6;
  int kh = lane >> 5, cl = lane & 31;
  int c_ = wv * 32 + cl;                     // col in slice, 0..255
  int gate = c_ >> 6, jj = c_ & 63;
  int gc = gate * 256 + s * 64 + jj;         // global gate column

  uint4 uu[16];                              // 128 f16 of U column (this k-half)
  {
    const unsigned* up = U + gc * 128 + kh * 64;
    #pragma unroll
    for (int i = 0; i < 16; i++) uu[i] = *(const uint4*)&up[i * 4];
  }
  #pragma unroll
  for (int i = 0; i < 16; i++)               // per-component pin: keep in VGPRs
    asm volatile("" : "+v"(uu[i].x), "+v"(uu[i].y), "+v"(uu[i].z), "+v"(uu[i].w));

  __shared__ unsigned h_lds[2][128];
  __shared__ float zsh[2][256];

  int ab = tid >> 6, aj = tid & 63;          // activation mapping (tid<128)
  int abb = b0 + (ab & 1);
  int alen = (tid < 128) ? lens[abb] : 0;
  float c_st = 0.f, h_st = 0.f;

  const unsigned* hl0 = &h_lds[0][kh * 64];
  const unsigned* hl1 = &h_lds[1][kh * 64];

  int pt = 0;
  for (int s_ = 0; s_ < 256; ++s_){
    int t = dir ? (255 - s_) : s_;
    // Z prefetch (one coalesced 8B load; independent of the exchange)
    uint2 zw = uint2{0u, 0u};
    if (tid < 128)
      zw = Zp[(size_t)(abb * 256 + t) * 256 + s * 64 + aj];
    if (s_ == 0){
      if (tid < 256) ((unsigned*)h_lds)[tid] = 0u;
    } else {
      if (tid < 256){
        const unsigned* ap = hg + pt * 256 + tid;
        unsigned w;
        do {
          w = __hip_atomic_load(ap, __ATOMIC_RELAXED, __HIP_MEMORY_SCOPE_AGENT);
        } while (w == SENT);
        ((unsigned*)h_lds)[tid] = w;
      }
    }
    __syncthreads();
    // matvec: z[c_] = sum_k U[k][gc] * h_prev[k], k-half per lane-half
    float a00 = 0.f, a01 = 0.f, a02 = 0.f, a03 = 0.f;
    float a10 = 0.f, a11 = 0.f, a12 = 0.f, a13 = 0.f;
    #pragma unroll
    for (int i = 0; i < 16; i++){
      uint4 h0 = *(const uint4*)&hl0[i * 4];
      uint4 h1 = *(const uint4*)&hl1[i * 4];
      a00 = fdot2(uu[i].x, h0.x, a00);  a01 = fdot2(uu[i].y, h0.y, a01);
      a02 = fdot2(uu[i].z, h0.z, a02);  a03 = fdot2(uu[i].w, h0.w, a03);
      a10 = fdot2(uu[i].x, h1.x, a10);  a11 = fdot2(uu[i].y, h1.y, a11);
      a12 = fdot2(uu[i].z, h1.z, a12);  a13 = fdot2(uu[i].w, h1.w, a13);
    }
    float zd0 = (a00 + a01) + (a02 + a03);
    float zd1 = (a10 + a11) + (a12 + a13);
    zd0 += __shfl_xor(zd0, 32);
    zd1 += __shfl_xor(zd1, 32);
    if (lane < 32){ zsh[0][c_] = zd0; zsh[1][c_] = zd1; }
    __syncthreads();
    if (tid < 128){
      float zi  = bf2f(zw.x & 0xffffu) + zsh[ab][aj];
      float zf2 = bf2f(zw.x >> 16)     + zsh[ab][64 + aj];
      float zg  = bf2f(zw.y & 0xffffu) + zsh[ab][128 + aj];
      float zo  = bf2f(zw.y >> 16)     + zsh[ab][192 + aj];
      if (t < alen){
        c_st = fsig(zf2) * c_st + fsig(zi) * ftanh(zg);
        h_st = fsig(zo) * ftanh(c_st);
      }
      unsigned hw = f2h(h_st);
      unsigned other = (unsigned)__shfl_xor((int)hw, 1);
      if ((aj & 1) == 0){                    // producer->consumer store FIRST
        unsigned word = hw | (other << 16);
        __hip_atomic_store(hg + t * 256 + ab * 128 + s * 32 + (aj >> 1), word,
                           __ATOMIC_RELAXED, __HIP_MEMORY_SCOPE_AGENT);
      }
      H[(size_t)(abb * 256 + t) * H_ + s * 64 + aj] = (ushort)hw;
    }
    pt = t;
  }
}

// ===== pot = [hf|hb] @ Wd + bd (one wave per row, f16 h) =====
__global__ __launch_bounds__(256) void k_pot(const ushort* __restrict__ hf16,
        const ushort* __restrict__ hb16, const float* __restrict__ Wd,
        const float* __restrict__ bd, float* __restrict__ out, int* __restrict__ cnt){
  if (blockIdx.x == 0 && threadIdx.x == 0) *cnt = 0;
  int lane = threadIdx.x & 63, wid = threadIdx.x >> 6;
  int m = blockIdx.x * 4 + wid;
  uint2 ua = *(const uint2*)&hf16[(size_t)m * H_ + lane * 4];
  uint2 ub = *(const uint2*)&hb16[(size_t)m * H_ + lane * 4];
  float av[4] = {h2lo(ua.x), h2hi(ua.x), h2lo(ua.y), h2hi(ua.y)};
  float bv[4] = {h2lo(ub.x), h2hi(ub.x), h2lo(ub.y), h2hi(ub.y)};
  float acc[9];
  #pragma unroll
  for (int l = 0; l < 9; l++) acc[l] = 0.f;
  #pragma unroll
  for (int i = 0; i < 4; i++){
    int r = lane * 4 + i;
    #pragma unroll
    for (int l = 0; l < 9; l++)
      acc[l] += av[i] * Wd[r * 9 + l] + bv[i] * Wd[(H_ + r) * 9 + l];
  }
  #pragma unroll
  for (int off = 32; off; off >>= 1)
    #pragma unroll
    for (int l = 0; l < 9; l++) acc[l] += __shfl_xor(acc[l], off);
  if (lane == 0){
    #pragma unroll
    for (int l = 0; l < 9; l++) out[(size_t)m * 9 + l] = acc[l] + bd[l];
  }
}

// ===== CRF log-likelihood + loss (fused, last-block reduce) =====
__global__ void k_post(const float* __restrict__ out, const int* __restrict__ tags,
                       const float* __restrict__ trans, const int* __restrict__ lens,
                       float* __restrict__ lln, int* cnt, float* __restrict__ loss_out){
  int b = blockIdx.x, lane = threadIdx.x;
  int len = lens[b];
  const float* pot = out + (size_t)b * T_ * 9;
  float up = 0.f, bp = 0.f;
  for (int t = lane; t < T_; t += 64){
    int tg = tags[b * T_ + t];
    if (t < len) up += pot[t * 9 + tg];
    if (t + 1 < len){
      int tg2 = tags[b * T_ + t + 1];
      bp += trans[tg * 9 + tg2];
    }
  }
  for (int off = 32; off; off >>= 1){ up += __shfl_xor(up, off); bp += __shfl_xor(bp, off); }
  float alpha = 0.f;
  if (lane < 9){
    float tr[9];
    #pragma unroll
    for (int i = 0; i < 9; i++) tr[i] = trans[i * 9 + lane];
    alpha = pot[lane];
    for (int t = 1; t < T_; ++t){
      float v[9];
      #pragma unroll
      for (int i = 0; i < 9; i++) v[i] = __shfl(alpha, i) + tr[i];
      float mx = v[0];
      #pragma unroll
      for (int i = 1; i < 9; i++) mx = fmaxf(mx, v[i]);
      float sum = 0.f;
      #pragma unroll
      for (int i = 0; i < 9; i++) sum += __expf(v[i] - mx);
      float an = pot[t * 9 + lane] + mx + __logf(sum);
      if (t < len) alpha = an;
    }
  }
  float mx2 = -3.4e38f;
  for (int i = 0; i < 9; i++){ float a = __shfl(alpha, i); mx2 = fmaxf(mx2, a); }
  float s2 = 0.f;
  for (int i = 0; i < 9; i++){ float a = __shfl(alpha, i); s2 += __expf(a - mx2); }
  float lse = mx2 + __logf(s2);
  __shared__ int lastf;
  if (lane == 0){
    __hip_atomic_store(&lln[b], (up + bp - lse) / (float)len,
                       __ATOMIC_RELAXED, __HIP_MEMORY_SCOPE_AGENT);
    int old = __hip_atomic_fetch_add(cnt, 1, __ATOMIC_ACQ_REL, __HIP_MEMORY_SCOPE_AGENT);
    lastf = (old == 63);
  }
  __syncthreads();
  if (lastf){
    float v = __hip_atomic_load(&lln[lane], __ATOMIC_RELAXED, __HIP_MEMORY_SCOPE_AGENT);
    for (int off = 32; off; off >>= 1) v += __shfl_xor(v, off);
    if (lane == 0) loss_out[0] = -v * (1.f / 64.f);
  }
}

extern "C" void kernel_launch(void* const* d_in, const int* in_sizes, int n_in,
                              void* d_out, int out_size, void* d_ws, size_t ws_size,
                              hipStream_t stream) {
  (void)in_sizes; (void)n_in; (void)out_size; (void)ws_size;
  const int*   inp   = (const int*)  d_in[0];
  const int*   tags  = (const int*)  d_in[1];
  const float* emb   = (const float*)d_in[2];
  const float* Wf    = (const float*)d_in[3];
  const float* Uf    = (const float*)d_in[4];
  const float* bfv   = (const float*)d_in[5];
  const float* Wb    = (const float*)d_in[6];
  const float* Ub    = (const float*)d_in[7];
  const float* bbv   = (const float*)d_in[8];
  const float* Wd    = (const float*)d_in[9];
  const float* bd    = (const float*)d_in[10];
  const float* trans = (const float*)d_in[11];
  float* out = (float*)d_out;

  char* ws = (char*)d_ws;
  unsigned* Upk2 = (unsigned*)(ws);                 // 1 MB
  ushort*   WT16 = (ushort*)  (ws + 1048576);       // 1 MB
  ushort*   Xbf  = (ushort*)  (ws + 2097152);       // 8 MB
  unsigned* hbuf = (unsigned*)(ws + 10485760);      // 16 MB
  int*      cnt  = (int*)     (ws + 10485760);      // aliases hbuf (dead by k_pot)
  ushort*   Zpf  = (ushort*)  (ws + 27262976);      // 32 MB packed bf16 [tok][j][g]
  ushort*   Zpb  = (ushort*)  (ws + 60817408);      // 32 MB
  ushort*   hf16 = (ushort*)  (ws + 94371840);      // 8 MB
  ushort*   hb16 = (ushort*)  (ws + 102760448);     // 8 MB
  int*      lens = (int*)     (ws + 111149056);     // 256 B
  float*    lln  = (float*)   (ws + 111149312);     // 256 B

  k_prep<<<9232, 256, 0, stream>>>(inp, emb, Wf, Wb, Uf, Ub, WT16, Upk2, Xbf,
                                   lens, out + 147456, (uint4*)hbuf);
  k_gemm<<<dim3(128, 8, 2), 256, 0, stream>>>(Xbf, WT16, bfv, bbv, Zpf, Zpb);
  k_recur6<<<256, 512, 0, stream>>>(Zpf, Zpb, Upk2, lens, hf16, hb16, hbuf);
  k_pot<<<4096, 256, 0, stream>>>(hf16, hb16, Wd, bd, out, cnt);
  k_post<<<64, 64, 0, stream>>>(out, tags, trans, lens, lln, cnt, out + 147520);
}

// Round 7
// 599.486 us; speedup vs baseline: 3.5889x; 1.0045x over previous
//
#include <hip/hip_runtime.h>

#define B_ 64
#define T_ 256
#define E_ 256
#define H_ 256
#define G4 1024   // 4*H
#define L_ 9
#define SENT 0xFFFFFFFFu

typedef __attribute__((ext_vector_type(8))) short bf16x8;
typedef __attribute__((ext_vector_type(4))) float f32x4;
typedef __attribute__((ext_vector_type(4))) unsigned uint4v;
typedef _Float16 half2v __attribute__((ext_vector_type(2)));

__device__ __forceinline__ ushort f2bf(float x){
  unsigned u = __float_as_uint(x);
  unsigned r = (u + 0x7FFFu + ((u >> 16) & 1u)) >> 16;
  return (ushort)r;
}
__device__ __forceinline__ ushort f2h(float x){
  _Float16 h = (_Float16)x;
  return __builtin_bit_cast(ushort, h);
}
__device__ __forceinline__ float h2lo(unsigned w){
  return (float)__builtin_bit_cast(half2v, w)[0];
}
__device__ __forceinline__ float h2hi(unsigned w){
  return (float)__builtin_bit_cast(half2v, w)[1];
}
__device__ __forceinline__ float bf2f(unsigned u16v){
  return __uint_as_float(u16v << 16);
}
__device__ __forceinline__ float fdot2(unsigned a, unsigned b, float c){
  return __builtin_amdgcn_fdot2(__builtin_bit_cast(half2v, a),
                                __builtin_bit_cast(half2v, b), c, false);
}
__device__ __forceinline__ float fsig(float x){
  return __builtin_amdgcn_rcpf(1.f + __expf(-x));
}
__device__ __forceinline__ float ftanh(float x){
  return 1.f - 2.f * __builtin_amdgcn_rcpf(__expf(2.f * x) + 1.f);
}

// ===== fused prep: WT | Upk2 | gather | hbuf-init | seqlen =====
__global__ void k_prep(const int* __restrict__ inp, const float* __restrict__ emb,
                       const float* __restrict__ Wf, const float* __restrict__ Wb,
                       const float* __restrict__ Uf, const float* __restrict__ Ub,
                       ushort* __restrict__ WT, unsigned* __restrict__ Upk2,
                       ushort* __restrict__ X, int* __restrict__ lens,
                       float* __restrict__ out_len, uint4* __restrict__ hbuf4){
  int bid = blockIdx.x, tid = threadIdx.x;
  if (bid < 2048){                                   // W -> bf16 transposed [dir][n][k]
    int idx = bid * 256 + tid;
    int dir = idx >> 18; int rem = idx & 262143;
    int n = rem >> 8, k = rem & 255;
    const float* W = dir ? Wb : Wf;
    WT[idx] = f2bf(W[k * G4 + n]);
  } else if (bid < 3072){                            // U -> f16 pairs [dir][gcol<1024][p<128]
    int idx = (bid - 2048) * 256 + tid;
    int dir = idx >> 17; int rem = idx & 131071;
    int gcol = rem >> 7, p = rem & 127;
    const float* U = dir ? Ub : Uf;
    unsigned lo = f2h(U[(2 * p) * G4 + gcol]);
    unsigned hi = f2h(U[(2 * p + 1) * G4 + gcol]);
    Upk2[idx] = lo | (hi << 16);
  } else if (bid < 5120){                            // X = bf16(emb[inp])
    int idx = (bid - 3072) * 256 + tid;
    int m = idx >> 5, koff = (idx & 31) * 8;
    int tok = inp[m];
    const float* src = emb + (size_t)tok * E_ + koff;
    float4 a = *(const float4*)src;
    float4 b = *(const float4*)(src + 4);
    uint4 o;
    o.x = (unsigned)f2bf(a.x) | ((unsigned)f2bf(a.y) << 16);
    o.y = (unsigned)f2bf(a.z) | ((unsigned)f2bf(a.w) << 16);
    o.z = (unsigned)f2bf(b.x) | ((unsigned)f2bf(b.y) << 16);
    o.w = (unsigned)f2bf(b.z) | ((unsigned)f2bf(b.w) << 16);
    *(uint4*)(X + m * E_ + koff) = o;
  } else if (bid < 9216){                            // hbuf = SENT (16 MB)
    int i = (bid - 5120) * 256 + tid;
    hbuf4[i] = uint4{SENT, SENT, SENT, SENT};
  } else {                                           // seq_lens: 16 blocks x 4 waves
    int w = tid >> 6, lane = tid & 63;
    int b = (bid - 9216) * 4 + w;
    int c = 0;
    for (int t = lane; t < T_; t += 64) c += (inp[b * T_ + t] != 0);
    for (int off = 32; off; off >>= 1) c += __shfl_xor(c, off);
    if (lane == 0){ lens[b] = c; out_len[b] = (float)c; }
  }
}

// ===== Z = X @ W + bias (bf16 MFMA) -> packed bf16 [tok][j<256][gate<4] =====
__global__ __launch_bounds__(256) void k_gemm(const ushort* __restrict__ X,
        const ushort* __restrict__ WT, const float* __restrict__ bf_,
        const float* __restrict__ bb_, ushort* __restrict__ Zpf, ushort* __restrict__ Zpb){
  int zi = blockIdx.z;
  const ushort* wt = WT + zi * 262144;
  const float* bias = zi ? bb_ : bf_;
  ushort* Zp = zi ? Zpb : Zpf;
  int m0 = blockIdx.x * 128, n0 = blockIdx.y * 128;
  __shared__ ushort As[128][40];
  __shared__ ushort Bs[128][40];
  int tid = threadIdx.x;
  int sr = tid >> 1, sk = (tid & 1) * 16;
  const ushort* xg = X + (m0 + sr) * E_ + sk;
  const ushort* wg = wt + (n0 + sr) * E_ + sk;
  f32x4 acc[4][4] = {};
  int lane = tid & 63, wv = tid >> 6;
  int wr = wv >> 1, wc = wv & 1;
  int lrow = lane & 15, kf = (lane >> 4) * 8;
  for (int k0 = 0; k0 < E_; k0 += 32){
    uint4 a0 = *(const uint4*)(xg + k0);
    uint4 a1 = *(const uint4*)(xg + k0 + 8);
    uint4 b0 = *(const uint4*)(wg + k0);
    uint4 b1 = *(const uint4*)(wg + k0 + 8);
    *(uint4*)&As[sr][sk]     = a0;  *(uint4*)&As[sr][sk + 8] = a1;
    *(uint4*)&Bs[sr][sk]     = b0;  *(uint4*)&Bs[sr][sk + 8] = b1;
    __syncthreads();
    bf16x8 af[4], bfr[4];
    #pragma unroll
    for (int i = 0; i < 4; i++) af[i]  = *(const bf16x8*)&As[wr * 64 + i * 16 + lrow][kf];
    #pragma unroll
    for (int i = 0; i < 4; i++) bfr[i] = *(const bf16x8*)&Bs[wc * 64 + i * 16 + lrow][kf];
    #pragma unroll
    for (int i = 0; i < 4; i++)
      #pragma unroll
      for (int j = 0; j < 4; j++)
        acc[i][j] = __builtin_amdgcn_mfma_f32_16x16x32_bf16(af[i], bfr[j], acc[i][j], 0, 0, 0);
    __syncthreads();
  }
  int crow = (lane >> 4) * 4;
  #pragma unroll
  for (int j = 0; j < 4; j++){
    int col = n0 + wc * 64 + j * 16 + lrow;
    float bv = bias[col];
    int gg = col >> 8, jj = col & 255;
    #pragma unroll
    for (int i = 0; i < 4; i++){
      int rbase = m0 + wr * 64 + i * 16 + crow;
      #pragma unroll
      for (int r = 0; r < 4; r++)
        Zp[((size_t)(rbase + r) * 256 + jj) * 4 + gg] = f2bf(acc[i][j][r] + bv);
    }
  }
}

// ===== LSTM recurrence v7: R6 structure + U in VGPRs via inline-asm loads =====
// grid 256: bid = s*64 + g, g = dir*32+bg. Peers 64 apart (same XCD, round-robin).
// 512 threads, 2 batches per WG. hg per group: [t][ab<2][p<128] unsigned f16-pair.
__global__ __launch_bounds__(512, 2) void k_recur7(
    const ushort* __restrict__ Zpf, const ushort* __restrict__ Zpb,
    const unsigned* __restrict__ Upk2, const int* __restrict__ lens,
    ushort* __restrict__ hf16, ushort* __restrict__ hb16,
    unsigned* hbuf){
  int bid = blockIdx.x;
  int g = bid & 63, s = bid >> 6;
  int dir = g >> 5, bg = g & 31;
  int b0 = bg * 2;
  const uint2* Zp = (const uint2*)(dir ? Zpb : Zpf);
  ushort* H = dir ? hb16 : hf16;
  const unsigned* U = Upk2 + dir * 131072;
  unsigned* hg = hbuf + g * 65536;

  int tid = threadIdx.x;
  int lane = tid & 63, wv = tid >> 6;
  int kh = lane >> 5, cl = lane & 31;
  int c_ = wv * 32 + cl;                     // col in slice, 0..255
  int gate = c_ >> 6, jj = c_ & 63;
  int gc = gate * 256 + s * 64 + jj;         // global gate column

  // U column (this k-half) in VGPRs, asm-defined => cannot be rematerialized
  uint4v uu[16];
  {
    const unsigned* up = U + gc * 128 + kh * 64;
    #pragma unroll
    for (int i = 0; i < 16; i++)
      asm volatile("global_load_dwordx4 %0, %1, off"
                   : "=v"(uu[i]) : "v"(up + i * 4));
    asm volatile("s_waitcnt vmcnt(0)" ::: "memory");
    __builtin_amdgcn_sched_barrier(0);
  }

  __shared__ unsigned h_lds[2][128];
  __shared__ float zsh[2][256];

  int ab = tid >> 6, aj = tid & 63;          // activation mapping (tid<128)
  int abb = b0 + (ab & 1);
  int alen = (tid < 128) ? lens[abb] : 0;
  float c_st = 0.f, h_st = 0.f;

  const unsigned* hl0 = &h_lds[0][kh * 64];
  const unsigned* hl1 = &h_lds[1][kh * 64];

  int pt = 0;
  for (int s_ = 0; s_ < 256; ++s_){
    int t = dir ? (255 - s_) : s_;
    // Z prefetch (one coalesced 8B load; independent of the exchange)
    uint2 zw = uint2{0u, 0u};
    if (tid < 128)
      zw = Zp[(size_t)(abb * 256 + t) * 256 + s * 64 + aj];
    if (s_ == 0){
      if (tid < 256) ((unsigned*)h_lds)[tid] = 0u;
    } else {
      if (tid < 256){
        const unsigned* ap = hg + pt * 256 + tid;
        unsigned w;
        do {
          w = __hip_atomic_load(ap, __ATOMIC_RELAXED, __HIP_MEMORY_SCOPE_AGENT);
        } while (w == SENT);
        ((unsigned*)h_lds)[tid] = w;
      }
    }
    __syncthreads();
    // matvec: z[c_] = sum_k U[k][gc] * h_prev[k], k-half per lane-half
    float a00 = 0.f, a01 = 0.f, a02 = 0.f, a03 = 0.f;
    float a10 = 0.f, a11 = 0.f, a12 = 0.f, a13 = 0.f;
    #pragma unroll
    for (int i = 0; i < 16; i++){
      uint4 h0 = *(const uint4*)&hl0[i * 4];
      uint4 h1 = *(const uint4*)&hl1[i * 4];
      a00 = fdot2(uu[i][0], h0.x, a00);  a01 = fdot2(uu[i][1], h0.y, a01);
      a02 = fdot2(uu[i][2], h0.z, a02);  a03 = fdot2(uu[i][3], h0.w, a03);
      a10 = fdot2(uu[i][0], h1.x, a10);  a11 = fdot2(uu[i][1], h1.y, a11);
      a12 = fdot2(uu[i][2], h1.z, a12);  a13 = fdot2(uu[i][3], h1.w, a13);
    }
    float zd0 = (a00 + a01) + (a02 + a03);
    float zd1 = (a10 + a11) + (a12 + a13);
    zd0 += __shfl_xor(zd0, 32);
    zd1 += __shfl_xor(zd1, 32);
    if (lane < 32){ zsh[0][c_] = zd0; zsh[1][c_] = zd1; }
    __syncthreads();
    if (tid < 128){
      float zi  = bf2f(zw.x & 0xffffu) + zsh[ab][aj];
      float zf2 = bf2f(zw.x >> 16)     + zsh[ab][64 + aj];
      float zg  = bf2f(zw.y & 0xffffu) + zsh[ab][128 + aj];
      float zo  = bf2f(zw.y >> 16)     + zsh[ab][192 + aj];
      if (t < alen){
        c_st = fsig(zf2) * c_st + fsig(zi) * ftanh(zg);
        h_st = fsig(zo) * ftanh(c_st);
      }
      unsigned hw = f2h(h_st);
      unsigned other = (unsigned)__shfl_xor((int)hw, 1);
      if ((aj & 1) == 0){                    // producer->consumer store FIRST
        unsigned word = hw | (other << 16);
        __hip_atomic_store(hg + t * 256 + ab * 128 + s * 32 + (aj >> 1), word,
                           __ATOMIC_RELAXED, __HIP_MEMORY_SCOPE_AGENT);
      }
      H[(size_t)(abb * 256 + t) * H_ + s * 64 + aj] = (ushort)hw;
    }
    pt = t;
  }
}

// ===== pot = [hf|hb] @ Wd + bd (one wave per row, f16 h) =====
__global__ __launch_bounds__(256) void k_pot(const ushort* __restrict__ hf16,
        const ushort* __restrict__ hb16, const float* __restrict__ Wd,
        const float* __restrict__ bd, float* __restrict__ out, int* __restrict__ cnt){
  if (blockIdx.x == 0 && threadIdx.x == 0) *cnt = 0;
  int lane = threadIdx.x & 63, wid = threadIdx.x >> 6;
  int m = blockIdx.x * 4 + wid;
  uint2 ua = *(const uint2*)&hf16[(size_t)m * H_ + lane * 4];
  uint2 ub = *(const uint2*)&hb16[(size_t)m * H_ + lane * 4];
  float av[4] = {h2lo(ua.x), h2hi(ua.x), h2lo(ua.y), h2hi(ua.y)};
  float bv[4] = {h2lo(ub.x), h2hi(ub.x), h2lo(ub.y), h2hi(ub.y)};
  float acc[9];
  #pragma unroll
  for (int l = 0; l < 9; l++) acc[l] = 0.f;
  #pragma unroll
  for (int i = 0; i < 4; i++){
    int r = lane * 4 + i;
    #pragma unroll
    for (int l = 0; l < 9; l++)
      acc[l] += av[i] * Wd[r * 9 + l] + bv[i] * Wd[(H_ + r) * 9 + l];
  }
  #pragma unroll
  for (int off = 32; off; off >>= 1)
    #pragma unroll
    for (int l = 0; l < 9; l++) acc[l] += __shfl_xor(acc[l], off);
  if (lane == 0){
    #pragma unroll
    for (int l = 0; l < 9; l++) out[(size_t)m * 9 + l] = acc[l] + bd[l];
  }
}

// ===== CRF log-likelihood + loss (fused, last-block reduce) =====
__global__ void k_post(const float* __restrict__ out, const int* __restrict__ tags,
                       const float* __restrict__ trans, const int* __restrict__ lens,
                       float* __restrict__ lln, int* cnt, float* __restrict__ loss_out){
  int b = blockIdx.x, lane = threadIdx.x;
  int len = lens[b];
  const float* pot = out + (size_t)b * T_ * 9;
  float up = 0.f, bp = 0.f;
  for (int t = lane; t < T_; t += 64){
    int tg = tags[b * T_ + t];
    if (t < len) up += pot[t * 9 + tg];
    if (t + 1 < len){
      int tg2 = tags[b * T_ + t + 1];
      bp += trans[tg * 9 + tg2];
    }
  }
  for (int off = 32; off; off >>= 1){ up += __shfl_xor(up, off); bp += __shfl_xor(bp, off); }
  float alpha = 0.f;
  if (lane < 9){
    float tr[9];
    #pragma unroll
    for (int i = 0; i < 9; i++) tr[i] = trans[i * 9 + lane];
    alpha = pot[lane];
    for (int t = 1; t < T_; ++t){
      float v[9];
      #pragma unroll
      for (int i = 0; i < 9; i++) v[i] = __shfl(alpha, i) + tr[i];
      float mx = v[0];
      #pragma unroll
      for (int i = 1; i < 9; i++) mx = fmaxf(mx, v[i]);
      float sum = 0.f;
      #pragma unroll
      for (int i = 0; i < 9; i++) sum += __expf(v[i] - mx);
      float an = pot[t * 9 + lane] + mx + __logf(sum);
      if (t < len) alpha = an;
    }
  }
  float mx2 = -3.4e38f;
  for (int i = 0; i < 9; i++){ float a = __shfl(alpha, i); mx2 = fmaxf(mx2, a); }
  float s2 = 0.f;
  for (int i = 0; i < 9; i++){ float a = __shfl(alpha, i); s2 += __expf(a - mx2); }
  float lse = mx2 + __logf(s2);
  __shared__ int lastf;
  if (lane == 0){
    __hip_atomic_store(&lln[b], (up + bp - lse) / (float)len,
                       __ATOMIC_RELAXED, __HIP_MEMORY_SCOPE_AGENT);
    int old = __hip_atomic_fetch_add(cnt, 1, __ATOMIC_ACQ_REL, __HIP_MEMORY_SCOPE_AGENT);
    lastf = (old == 63);
  }
  __syncthreads();
  if (lastf){
    float v = __hip_atomic_load(&lln[lane], __ATOMIC_RELAXED, __HIP_MEMORY_SCOPE_AGENT);
    for (int off = 32; off; off >>= 1) v += __shfl_xor(v, off);
    if (lane == 0) loss_out[0] = -v * (1.f / 64.f);
  }
}

extern "C" void kernel_launch(void* const* d_in, const int* in_sizes, int n_in,
                              void* d_out, int out_size, void* d_ws, size_t ws_size,
                              hipStream_t stream) {
  (void)in_sizes; (void)n_in; (void)out_size; (void)ws_size;
  const int*   inp   = (const int*)  d_in[0];
  const int*   tags  = (const int*)  d_in[1];
  const float* emb   = (const float*)d_in[2];
  const float* Wf    = (const float*)d_in[3];
  const float* Uf    = (const float*)d_in[4];
  const float* bfv   = (const float*)d_in[5];
  const float* Wb    = (const float*)d_in[6];
  const float* Ub    = (const float*)d_in[7];
  const float* bbv   = (const float*)d_in[8];
  const float* Wd    = (const float*)d_in[9];
  const float* bd    = (const float*)d_in[10];
  const float* trans = (const float*)d_in[11];
  float* out = (float*)d_out;

  char* ws = (char*)d_ws;
  unsigned* Upk2 = (unsigned*)(ws);                 // 1 MB
  ushort*   WT16 = (ushort*)  (ws + 1048576);       // 1 MB
  ushort*   Xbf  = (ushort*)  (ws + 2097152);       // 8 MB
  unsigned* hbuf = (unsigned*)(ws + 10485760);      // 16 MB
  int*      cnt  = (int*)     (ws + 10485760);      // aliases hbuf (dead by k_pot)
  ushort*   Zpf  = (ushort*)  (ws + 27262976);      // 32 MB packed bf16 [tok][j][g]
  ushort*   Zpb  = (ushort*)  (ws + 60817408);      // 32 MB
  ushort*   hf16 = (ushort*)  (ws + 94371840);      // 8 MB
  ushort*   hb16 = (ushort*)  (ws + 102760448);     // 8 MB
  int*      lens = (int*)     (ws + 111149056);     // 256 B
  float*    lln  = (float*)   (ws + 111149312);     // 256 B

  k_prep<<<9232, 256, 0, stream>>>(inp, emb, Wf, Wb, Uf, Ub, WT16, Upk2, Xbf,
                                   lens, out + 147456, (uint4*)hbuf);
  k_gemm<<<dim3(128, 8, 2), 256, 0, stream>>>(Xbf, WT16, bfv, bbv, Zpf, Zpb);
  k_recur7<<<256, 512, 0, stream>>>(Zpf, Zpb, Upk2, lens, hf16, hb16, hbuf);
  k_pot<<<4096, 256, 0, stream>>>(hf16, hb16, Wd, bd, out, cnt);
  k_post<<<64, 64, 0, stream>>>(out, tags, trans, lens, lln, cnt, out + 147520);
}

// Round 8
// 417.581 us; speedup vs baseline: 5.1523x; 1.4356x over previous
//
#include <hip/hip_runtime.h>

#define B_ 64
#define T_ 256
#define E_ 256
#define H_ 256
#define G4 1024   // 4*H
#define L_ 9

typedef __attribute__((ext_vector_type(8))) short bf16x8;
typedef __attribute__((ext_vector_type(4))) float f32x4;
typedef _Float16 half2v __attribute__((ext_vector_type(2)));

__device__ __forceinline__ ushort f2bf(float x){
  unsigned u = __float_as_uint(x);
  unsigned r = (u + 0x7FFFu + ((u >> 16) & 1u)) >> 16;
  return (ushort)r;
}
__device__ __forceinline__ float bf2f(unsigned u16v){
  return __uint_as_float(u16v << 16);
}
__device__ __forceinline__ float fsig(float x){
  return __builtin_amdgcn_rcpf(1.f + __expf(-x));
}
__device__ __forceinline__ float ftanh(float x){
  return 1.f - 2.f * __builtin_amdgcn_rcpf(__expf(2.f * x) + 1.f);
}
__device__ __forceinline__ int sdot4(unsigned a, unsigned b, int c){
#if __has_builtin(__builtin_amdgcn_sdot4)
  return __builtin_amdgcn_sdot4((int)a, (int)b, c, false);
#else
  int r = c;
  #pragma unroll
  for (int j = 0; j < 4; j++){
    int av = (int)(signed char)((a >> (8 * j)) & 0xFF);
    int bv = (int)(signed char)((b >> (8 * j)) & 0xFF);
    r += av * bv;
  }
  return r;
#endif
}

// ===== fused prep: WT | Uq(i8 quant) | gather | seqlen =====
__global__ void k_prep(const int* __restrict__ inp, const float* __restrict__ emb,
                       const float* __restrict__ Wf, const float* __restrict__ Wb,
                       const float* __restrict__ Uf, const float* __restrict__ Ub,
                       ushort* __restrict__ WT, unsigned* __restrict__ Uq,
                       float* __restrict__ su, ushort* __restrict__ X,
                       int* __restrict__ lens, float* __restrict__ out_len){
  int bid = blockIdx.x, tid = threadIdx.x;
  if (bid < 2048){                                   // W -> bf16 transposed [dir][n][k]
    int idx = bid * 256 + tid;
    int dir = idx >> 18; int rem = idx & 262143;
    int n = rem >> 8, k = rem & 255;
    const float* W = dir ? Wb : Wf;
    WT[idx] = f2bf(W[k * G4 + n]);
  } else if (bid < 4096){                            // U column -> i8 [dir][kq<64][c<1024]
    int idx = bid - 2048;                            // dir*1024 + c
    int dir = idx >> 10, cc = idx & 1023;
    const float* U = dir ? Ub : Uf;
    float v = U[tid * G4 + cc];                      // tid = k
    __shared__ float red[4];
    __shared__ float ssu;
    __shared__ char qb[256];
    float a = fabsf(v);
    #pragma unroll
    for (int off = 32; off; off >>= 1) a = fmaxf(a, __shfl_xor(a, off));
    int lane = tid & 63, w = tid >> 6;
    if (lane == 0) red[w] = a;
    __syncthreads();
    if (tid == 0){
      float m = fmaxf(fmaxf(red[0], red[1]), fmaxf(red[2], red[3]));
      float s = fmaxf(m, 1e-20f) * (1.f / 127.f);
      ssu = s;
      su[idx] = s;
    }
    __syncthreads();
    float s = ssu;
    int q = __float2int_rn(v / s);
    q = max(-127, min(127, q));
    qb[tid] = (char)q;
    __syncthreads();
    if (tid < 64)
      Uq[dir * 65536 + tid * 1024 + cc] = *(const unsigned*)&qb[tid * 4];
  } else if (bid < 6144){                            // X = bf16(emb[inp])
    int idx = (bid - 4096) * 256 + tid;
    int m = idx >> 5, koff = (idx & 31) * 8;
    int tok = inp[m];
    const float* src = emb + (size_t)tok * E_ + koff;
    float4 a = *(const float4*)src;
    float4 b = *(const float4*)(src + 4);
    uint4 o;
    o.x = (unsigned)f2bf(a.x) | ((unsigned)f2bf(a.y) << 16);
    o.y = (unsigned)f2bf(a.z) | ((unsigned)f2bf(a.w) << 16);
    o.z = (unsigned)f2bf(b.x) | ((unsigned)f2bf(b.y) << 16);
    o.w = (unsigned)f2bf(b.z) | ((unsigned)f2bf(b.w) << 16);
    *(uint4*)(X + m * E_ + koff) = o;
  } else {                                           // seq_lens: 16 blocks x 4 waves
    int w = tid >> 6, lane = tid & 63;
    int b = (bid - 6144) * 4 + w;
    int c = 0;
    for (int t = lane; t < T_; t += 64) c += (inp[b * T_ + t] != 0);
    for (int off = 32; off; off >>= 1) c += __shfl_xor(c, off);
    if (lane == 0){ lens[b] = c; out_len[b] = (float)c; }
  }
}

// ===== Z = X @ W + bias (bf16 MFMA) -> packed bf16 [tok][j<256][gate<4] =====
__global__ __launch_bounds__(256) void k_gemm(const ushort* __restrict__ X,
        const ushort* __restrict__ WT, const float* __restrict__ bf_,
        const float* __restrict__ bb_, ushort* __restrict__ Zpf, ushort* __restrict__ Zpb){
  int zi = blockIdx.z;
  const ushort* wt = WT + zi * 262144;
  const float* bias = zi ? bb_ : bf_;
  ushort* Zp = zi ? Zpb : Zpf;
  int m0 = blockIdx.x * 128, n0 = blockIdx.y * 128;
  __shared__ ushort As[128][40];
  __shared__ ushort Bs[128][40];
  int tid = threadIdx.x;
  int sr = tid >> 1, sk = (tid & 1) * 16;
  const ushort* xg = X + (m0 + sr) * E_ + sk;
  const ushort* wg = wt + (n0 + sr) * E_ + sk;
  f32x4 acc[4][4] = {};
  int lane = tid & 63, wv = tid >> 6;
  int wr = wv >> 1, wc = wv & 1;
  int lrow = lane & 15, kf = (lane >> 4) * 8;
  for (int k0 = 0; k0 < E_; k0 += 32){
    uint4 a0 = *(const uint4*)(xg + k0);
    uint4 a1 = *(const uint4*)(xg + k0 + 8);
    uint4 b0 = *(const uint4*)(wg + k0);
    uint4 b1 = *(const uint4*)(wg + k0 + 8);
    *(uint4*)&As[sr][sk]     = a0;  *(uint4*)&As[sr][sk + 8] = a1;
    *(uint4*)&Bs[sr][sk]     = b0;  *(uint4*)&Bs[sr][sk + 8] = b1;
    __syncthreads();
    bf16x8 af[4], bfr[4];
    #pragma unroll
    for (int i = 0; i < 4; i++) af[i]  = *(const bf16x8*)&As[wr * 64 + i * 16 + lrow][kf];
    #pragma unroll
    for (int i = 0; i < 4; i++) bfr[i] = *(const bf16x8*)&Bs[wc * 64 + i * 16 + lrow][kf];
    #pragma unroll
    for (int i = 0; i < 4; i++)
      #pragma unroll
      for (int j = 0; j < 4; j++)
        acc[i][j] = __builtin_amdgcn_mfma_f32_16x16x32_bf16(af[i], bfr[j], acc[i][j], 0, 0, 0);
    __syncthreads();
  }
  int crow = (lane >> 4) * 4;
  #pragma unroll
  for (int j = 0; j < 4; j++){
    int col = n0 + wc * 64 + j * 16 + lrow;
    float bv = bias[col];
    int gg = col >> 8, jj = col & 255;
    #pragma unroll
    for (int i = 0; i < 4; i++){
      int rbase = m0 + wr * 64 + i * 16 + crow;
      #pragma unroll
      for (int r = 0; r < 4; r++)
        Zp[((size_t)(rbase + r) * 256 + jj) * 4 + gg] = f2bf(acc[i][j][r] + bv);
    }
  }
}

// ===== LSTM recurrence v8: one WG per (dir,batch), i8 U in regs, LDS-only h =====
// 128 WGs x 1024 thr. Thread tid owns gate-column c=tid (full k=256).
// hq: i8-packed h (64 u32), double-buffered in LDS. No inter-WG traffic at all.
__global__ __launch_bounds__(1024, 4) void k_recur8(
    const ushort* __restrict__ Zpf, const ushort* __restrict__ Zpb,
    const unsigned* __restrict__ Uq, const float* __restrict__ su,
    const int* __restrict__ lens, ushort* __restrict__ hf16, ushort* __restrict__ hb16){
  int bid = blockIdx.x;
  int dir = bid >> 6, b = bid & 63;
  const uint2* Zp = (const uint2*)(dir ? Zpb : Zpf);
  ushort* H = dir ? hb16 : hf16;
  const unsigned* Uqd = Uq + dir * 65536;        // [kq][c]
  int tid = threadIdx.x;                          // = column c
  float sc = su[dir * 1024 + tid] * (1.f / 127.f);
  int alen = lens[b];

  // U column in regs (64 u32 of packed i8), asm-defined so it can't be re-sunk
  unsigned uq[64];
  {
    const unsigned* p = Uqd + tid;
    #pragma unroll
    for (int i = 0; i < 64; i++){
      asm volatile("global_load_dword %0, %1, off" : "=v"(uq[i]) : "v"(p));
      p += 1024;
    }
    asm volatile("s_waitcnt vmcnt(0)" ::: "memory");
    __builtin_amdgcn_sched_barrier(0);
  }

  __shared__ float zsh[1024];
  __shared__ unsigned hq[2][64];

  if (tid < 64){ hq[0][tid] = 0u; }
  __syncthreads();

  float c_st = 0.f, h_st = 0.f;
  int t0 = dir ? 255 : 0;
  uint2 zw = uint2{0u, 0u};
  if (tid < 256) zw = Zp[(size_t)(b * 256 + t0) * 256 + tid];

  for (int s_ = 0; s_ < 256; ++s_){
    int t = dir ? (255 - s_) : s_;
    int tn = dir ? (t - 1) : (t + 1);
    int cur = s_ & 1, nxt = cur ^ 1;
    // prefetch next step's Z (1 step of latency cover)
    uint2 zw_n = uint2{0u, 0u};
    if (tid < 256 && s_ < 255) zw_n = Zp[(size_t)(b * 256 + tn) * 256 + tid];
    // matvec: z[c] = sum_k Uq[k][c] * hq[k]  (i8 dot4, h broadcast from LDS)
    int acc0 = 0, acc1 = 0;
    const uint4* hp = (const uint4*)hq[cur];
    #pragma unroll
    for (int i = 0; i < 16; i++){
      uint4 hv = hp[i];
      acc0 = sdot4(uq[4 * i + 0], hv.x, acc0);
      acc1 = sdot4(uq[4 * i + 1], hv.y, acc1);
      acc0 = sdot4(uq[4 * i + 2], hv.z, acc0);
      acc1 = sdot4(uq[4 * i + 3], hv.w, acc1);
    }
    zsh[tid] = (float)(acc0 + acc1) * sc;
    __syncthreads();
    if (tid < 256){
      float zi = bf2f(zw.x & 0xffffu) + zsh[tid];
      float zf = bf2f(zw.x >> 16)     + zsh[256 + tid];
      float zg = bf2f(zw.y & 0xffffu) + zsh[512 + tid];
      float zo = bf2f(zw.y >> 16)     + zsh[768 + tid];
      if (t < alen){
        c_st = fsig(zf) * c_st + fsig(zi) * ftanh(zg);
        h_st = fsig(zo) * ftanh(c_st);
      }
      // i8-quantized h for next step
      int ri = __float2int_rn(h_st * 127.f);
      ((char*)hq[nxt])[tid] = (char)ri;
      // bf16 h out (pair-packed u32 stores)
      unsigned hw = f2bf(h_st);
      unsigned other = (unsigned)__shfl_xor((int)hw, 1);
      if (!(tid & 1)){
        unsigned word = hw | (other << 16);
        *(unsigned*)&H[(size_t)(b * 256 + t) * H_ + tid] = word;
      }
    }
    __syncthreads();
    zw = zw_n;
  }
}

// ===== pot = [hf|hb] @ Wd + bd (one wave per row, bf16 h) =====
__global__ __launch_bounds__(256) void k_pot(const ushort* __restrict__ hf16,
        const ushort* __restrict__ hb16, const float* __restrict__ Wd,
        const float* __restrict__ bd, float* __restrict__ out, int* __restrict__ cnt){
  if (blockIdx.x == 0 && threadIdx.x == 0) *cnt = 0;
  int lane = threadIdx.x & 63, wid = threadIdx.x >> 6;
  int m = blockIdx.x * 4 + wid;
  uint2 ua = *(const uint2*)&hf16[(size_t)m * H_ + lane * 4];
  uint2 ub = *(const uint2*)&hb16[(size_t)m * H_ + lane * 4];
  float av[4] = {bf2f(ua.x & 0xFFFFu), bf2f(ua.x >> 16), bf2f(ua.y & 0xFFFFu), bf2f(ua.y >> 16)};
  float bv[4] = {bf2f(ub.x & 0xFFFFu), bf2f(ub.x >> 16), bf2f(ub.y & 0xFFFFu), bf2f(ub.y >> 16)};
  float acc[9];
  #pragma unroll
  for (int l = 0; l < 9; l++) acc[l] = 0.f;
  #pragma unroll
  for (int i = 0; i < 4; i++){
    int r = lane * 4 + i;
    #pragma unroll
    for (int l = 0; l < 9; l++)
      acc[l] += av[i] * Wd[r * 9 + l] + bv[i] * Wd[(H_ + r) * 9 + l];
  }
  #pragma unroll
  for (int off = 32; off; off >>= 1)
    #pragma unroll
    for (int l = 0; l < 9; l++) acc[l] += __shfl_xor(acc[l], off);
  if (lane == 0){
    #pragma unroll
    for (int l = 0; l < 9; l++) out[(size_t)m * 9 + l] = acc[l] + bd[l];
  }
}

// ===== CRF log-likelihood + loss (fused, last-block reduce) =====
__global__ void k_post(const float* __restrict__ out, const int* __restrict__ tags,
                       const float* __restrict__ trans, const int* __restrict__ lens,
                       float* __restrict__ lln, int* cnt, float* __restrict__ loss_out){
  int b = blockIdx.x, lane = threadIdx.x;
  int len = lens[b];
  const float* pot = out + (size_t)b * T_ * 9;
  float up = 0.f, bp = 0.f;
  for (int t = lane; t < T_; t += 64){
    int tg = tags[b * T_ + t];
    if (t < len) up += pot[t * 9 + tg];
    if (t + 1 < len){
      int tg2 = tags[b * T_ + t + 1];
      bp += trans[tg * 9 + tg2];
    }
  }
  for (int off = 32; off; off >>= 1){ up += __shfl_xor(up, off); bp += __shfl_xor(bp, off); }
  float alpha = 0.f;
  if (lane < 9){
    float tr[9];
    #pragma unroll
    for (int i = 0; i < 9; i++) tr[i] = trans[i * 9 + lane];
    alpha = pot[lane];
    for (int t = 1; t < T_; ++t){
      float v[9];
      #pragma unroll
      for (int i = 0; i < 9; i++) v[i] = __shfl(alpha, i) + tr[i];
      float mx = v[0];
      #pragma unroll
      for (int i = 1; i < 9; i++) mx = fmaxf(mx, v[i]);
      float sum = 0.f;
      #pragma unroll
      for (int i = 0; i < 9; i++) sum += __expf(v[i] - mx);
      float an = pot[t * 9 + lane] + mx + __logf(sum);
      if (t < len) alpha = an;
    }
  }
  float mx2 = -3.4e38f;
  for (int i = 0; i < 9; i++){ float a = __shfl(alpha, i); mx2 = fmaxf(mx2, a); }
  float s2 = 0.f;
  for (int i = 0; i < 9; i++){ float a = __shfl(alpha, i); s2 += __expf(a - mx2); }
  float lse = mx2 + __logf(s2);
  __shared__ int lastf;
  if (lane == 0){
    __hip_atomic_store(&lln[b], (up + bp - lse) / (float)len,
                       __ATOMIC_RELAXED, __HIP_MEMORY_SCOPE_AGENT);
    int old = __hip_atomic_fetch_add(cnt, 1, __ATOMIC_ACQ_REL, __HIP_MEMORY_SCOPE_AGENT);
    lastf = (old == 63);
  }
  __syncthreads();
  if (lastf){
    float v = __hip_atomic_load(&lln[lane], __ATOMIC_RELAXED, __HIP_MEMORY_SCOPE_AGENT);
    for (int off = 32; off; off >>= 1) v += __shfl_xor(v, off);
    if (lane == 0) loss_out[0] = -v * (1.f / 64.f);
  }
}

extern "C" void kernel_launch(void* const* d_in, const int* in_sizes, int n_in,
                              void* d_out, int out_size, void* d_ws, size_t ws_size,
                              hipStream_t stream) {
  (void)in_sizes; (void)n_in; (void)out_size; (void)ws_size;
  const int*   inp   = (const int*)  d_in[0];
  const int*   tags  = (const int*)  d_in[1];
  const float* emb   = (const float*)d_in[2];
  const float* Wf    = (const float*)d_in[3];
  const float* Uf    = (const float*)d_in[4];
  const float* bfv   = (const float*)d_in[5];
  const float* Wb    = (const float*)d_in[6];
  const float* Ub    = (const float*)d_in[7];
  const float* bbv   = (const float*)d_in[8];
  const float* Wd    = (const float*)d_in[9];
  const float* bd    = (const float*)d_in[10];
  const float* trans = (const float*)d_in[11];
  float* out = (float*)d_out;

  char* ws = (char*)d_ws;
  unsigned* Uq   = (unsigned*)(ws);                 // 512 KB
  float*    su   = (float*)   (ws + 524288);        // 8 KB
  ushort*   WT16 = (ushort*)  (ws + 1048576);       // 1 MB
  ushort*   Xbf  = (ushort*)  (ws + 2097152);       // 8 MB
  int*      cnt  = (int*)     (ws + 2097152);       // aliases Xbf (dead by k_pot)
  ushort*   Zpf  = (ushort*)  (ws + 10485760);      // 32 MB packed bf16 [tok][j][g]
  ushort*   Zpb  = (ushort*)  (ws + 44040192);      // 32 MB
  ushort*   hf16 = (ushort*)  (ws + 77594624);      // 8 MB
  ushort*   hb16 = (ushort*)  (ws + 85983232);      // 8 MB
  int*      lens = (int*)     (ws + 94371840);      // 256 B
  float*    lln  = (float*)   (ws + 94372096);      // 256 B

  k_prep<<<6160, 256, 0, stream>>>(inp, emb, Wf, Wb, Uf, Ub, WT16, Uq, su, Xbf,
                                   lens, out + 147456);
  k_gemm<<<dim3(128, 8, 2), 256, 0, stream>>>(Xbf, WT16, bfv, bbv, Zpf, Zpb);
  k_recur8<<<128, 1024, 0, stream>>>(Zpf, Zpb, Uq, su, lens, hf16, hb16);
  k_pot<<<4096, 256, 0, stream>>>(hf16, hb16, Wd, bd, out, cnt);
  k_post<<<64, 64, 0, stream>>>(out, tags, trans, lens, lln, cnt, out + 147520);
}

// Round 9
// 408.712 us; speedup vs baseline: 5.2641x; 1.0217x over previous
//
#include <hip/hip_runtime.h>

#define B_ 64
#define T_ 256
#define E_ 256
#define H_ 256
#define G4 1024   // 4*H
#define L_ 9

typedef __attribute__((ext_vector_type(8))) short bf16x8;
typedef __attribute__((ext_vector_type(4))) float f32x4;
typedef __attribute__((ext_vector_type(4))) unsigned uint4v;
typedef _Float16 half2v __attribute__((ext_vector_type(2)));

__device__ __forceinline__ ushort f2bf(float x){
  unsigned u = __float_as_uint(x);
  unsigned r = (u + 0x7FFFu + ((u >> 16) & 1u)) >> 16;
  return (ushort)r;
}
__device__ __forceinline__ float bf2f(unsigned u16v){
  return __uint_as_float(u16v << 16);
}
__device__ __forceinline__ float fsig(float x){
  return __builtin_amdgcn_rcpf(1.f + __expf(-x));
}
__device__ __forceinline__ float ftanh(float x){
  return 1.f - 2.f * __builtin_amdgcn_rcpf(__expf(2.f * x) + 1.f);
}
__device__ __forceinline__ int sdot4(unsigned a, unsigned b, int c){
#if __has_builtin(__builtin_amdgcn_sdot4)
  return __builtin_amdgcn_sdot4((int)a, (int)b, c, false);
#else
  int r = c;
  #pragma unroll
  for (int j = 0; j < 4; j++){
    int av = (int)(signed char)((a >> (8 * j)) & 0xFF);
    int bv = (int)(signed char)((b >> (8 * j)) & 0xFF);
    r += av * bv;
  }
  return r;
#endif
}

// ===== fused prep: WT | Uq(i8 quant, col-major) | gather | seqlen =====
__global__ void k_prep(const int* __restrict__ inp, const float* __restrict__ emb,
                       const float* __restrict__ Wf, const float* __restrict__ Wb,
                       const float* __restrict__ Uf, const float* __restrict__ Ub,
                       ushort* __restrict__ WT, unsigned* __restrict__ Uq,
                       float* __restrict__ su, ushort* __restrict__ X,
                       int* __restrict__ lens, float* __restrict__ out_len){
  int bid = blockIdx.x, tid = threadIdx.x;
  if (bid < 2048){                                   // W -> bf16 transposed [dir][n][k]
    int idx = bid * 256 + tid;
    int dir = idx >> 18; int rem = idx & 262143;
    int n = rem >> 8, k = rem & 255;
    const float* W = dir ? Wb : Wf;
    WT[idx] = f2bf(W[k * G4 + n]);
  } else if (bid < 4096){                            // U column -> i8 [dir][c<1024][kq<64]
    int idx = bid - 2048;                            // dir*1024 + c
    int dir = idx >> 10, cc = idx & 1023;
    const float* U = dir ? Ub : Uf;
    float v = U[tid * G4 + cc];                      // tid = k
    __shared__ float red[4];
    __shared__ float ssu;
    __shared__ char qb[256];
    float a = fabsf(v);
    #pragma unroll
    for (int off = 32; off; off >>= 1) a = fmaxf(a, __shfl_xor(a, off));
    int lane = tid & 63, w = tid >> 6;
    if (lane == 0) red[w] = a;
    __syncthreads();
    if (tid == 0){
      float m = fmaxf(fmaxf(red[0], red[1]), fmaxf(red[2], red[3]));
      float s = fmaxf(m, 1e-20f) * (1.f / 127.f);
      ssu = s;
      su[idx] = s;
    }
    __syncthreads();
    float s = ssu;
    int q = __float2int_rn(v / s);
    q = max(-127, min(127, q));
    qb[tid] = (char)q;
    __syncthreads();
    if (tid < 64)
      Uq[dir * 65536 + cc * 64 + tid] = *(const unsigned*)&qb[tid * 4];
  } else if (bid < 6144){                            // X = bf16(emb[inp])
    int idx = (bid - 4096) * 256 + tid;
    int m = idx >> 5, koff = (idx & 31) * 8;
    int tok = inp[m];
    const float* src = emb + (size_t)tok * E_ + koff;
    float4 a = *(const float4*)src;
    float4 b = *(const float4*)(src + 4);
    uint4 o;
    o.x = (unsigned)f2bf(a.x) | ((unsigned)f2bf(a.y) << 16);
    o.y = (unsigned)f2bf(a.z) | ((unsigned)f2bf(a.w) << 16);
    o.z = (unsigned)f2bf(b.x) | ((unsigned)f2bf(b.y) << 16);
    o.w = (unsigned)f2bf(b.z) | ((unsigned)f2bf(b.w) << 16);
    *(uint4*)(X + m * E_ + koff) = o;
  } else {                                           // seq_lens: 16 blocks x 4 waves
    int w = tid >> 6, lane = tid & 63;
    int b = (bid - 6144) * 4 + w;
    int c = 0;
    for (int t = lane; t < T_; t += 64) c += (inp[b * T_ + t] != 0);
    for (int off = 32; off; off >>= 1) c += __shfl_xor(c, off);
    if (lane == 0){ lens[b] = c; out_len[b] = (float)c; }
  }
}

// ===== Z = X @ W + bias (bf16 MFMA) -> packed bf16 [tok][j<256][gate<4] =====
__global__ __launch_bounds__(256) void k_gemm(const ushort* __restrict__ X,
        const ushort* __restrict__ WT, const float* __restrict__ bf_,
        const float* __restrict__ bb_, ushort* __restrict__ Zpf, ushort* __restrict__ Zpb){
  int zi = blockIdx.z;
  const ushort* wt = WT + zi * 262144;
  const float* bias = zi ? bb_ : bf_;
  ushort* Zp = zi ? Zpb : Zpf;
  int m0 = blockIdx.x * 128, n0 = blockIdx.y * 128;
  __shared__ ushort As[128][40];
  __shared__ ushort Bs[128][40];
  int tid = threadIdx.x;
  int sr = tid >> 1, sk = (tid & 1) * 16;
  const ushort* xg = X + (m0 + sr) * E_ + sk;
  const ushort* wg = wt + (n0 + sr) * E_ + sk;
  f32x4 acc[4][4] = {};
  int lane = tid & 63, wv = tid >> 6;
  int wr = wv >> 1, wc = wv & 1;
  int lrow = lane & 15, kf = (lane >> 4) * 8;
  for (int k0 = 0; k0 < E_; k0 += 32){
    uint4 a0 = *(const uint4*)(xg + k0);
    uint4 a1 = *(const uint4*)(xg + k0 + 8);
    uint4 b0 = *(const uint4*)(wg + k0);
    uint4 b1 = *(const uint4*)(wg + k0 + 8);
    *(uint4*)&As[sr][sk]     = a0;  *(uint4*)&As[sr][sk + 8] = a1;
    *(uint4*)&Bs[sr][sk]     = b0;  *(uint4*)&Bs[sr][sk + 8] = b1;
    __syncthreads();
    bf16x8 af[4], bfr[4];
    #pragma unroll
    for (int i = 0; i < 4; i++) af[i]  = *(const bf16x8*)&As[wr * 64 + i * 16 + lrow][kf];
    #pragma unroll
    for (int i = 0; i < 4; i++) bfr[i] = *(const bf16x8*)&Bs[wc * 64 + i * 16 + lrow][kf];
    #pragma unroll
    for (int i = 0; i < 4; i++)
      #pragma unroll
      for (int j = 0; j < 4; j++)
        acc[i][j] = __builtin_amdgcn_mfma_f32_16x16x32_bf16(af[i], bfr[j], acc[i][j], 0, 0, 0);
    __syncthreads();
  }
  int crow = (lane >> 4) * 4;
  #pragma unroll
  for (int j = 0; j < 4; j++){
    int col = n0 + wc * 64 + j * 16 + lrow;
    float bv = bias[col];
    int gg = col >> 8, jj = col & 255;
    #pragma unroll
    for (int i = 0; i < 4; i++){
      int rbase = m0 + wr * 64 + i * 16 + crow;
      #pragma unroll
      for (int r = 0; r < 4; r++)
        Zp[((size_t)(rbase + r) * 256 + jj) * 4 + gg] = f2bf(acc[i][j][r] + bv);
    }
  }
}

// ===== LSTM recurrence v9: 512 thr, 2 cols/thread, VGPR cap 256 (no AGPR copies) =====
// 128 WGs x 512 thr. Thread tid owns cols c0=tid, c1=tid+512 (full k=256 each).
// U in arch VGPRs (32x dwordx4 asm loads from col-major Uq). h i8 in LDS only.
__global__ __launch_bounds__(512, 2) void k_recur9(
    const ushort* __restrict__ Zpf, const ushort* __restrict__ Zpb,
    const unsigned* __restrict__ Uq, const float* __restrict__ su,
    const int* __restrict__ lens, ushort* __restrict__ hf16, ushort* __restrict__ hb16){
  int bid = blockIdx.x;
  int dir = bid >> 6, b = bid & 63;
  const uint2* Zp = (const uint2*)(dir ? Zpb : Zpf);
  ushort* H = dir ? hb16 : hf16;
  const unsigned* Uqd = Uq + dir * 65536;        // [c][kq]
  int tid = threadIdx.x;
  int c0 = tid, c1 = tid + 512;
  float scA = su[dir * 1024 + c0] * (1.f / 127.f);
  float scB = su[dir * 1024 + c1] * (1.f / 127.f);
  int alen = lens[b];

  // two U columns in arch VGPRs (asm-defined: cannot be rematerialized)
  uint4v uqA[16], uqB[16];
  {
    const unsigned* pa = Uqd + c0 * 64;
    const unsigned* pb = Uqd + c1 * 64;
    #pragma unroll
    for (int i = 0; i < 16; i++){
      asm volatile("global_load_dwordx4 %0, %1, off" : "=v"(uqA[i]) : "v"(pa + 4 * i));
      asm volatile("global_load_dwordx4 %0, %1, off" : "=v"(uqB[i]) : "v"(pb + 4 * i));
    }
    asm volatile("s_waitcnt vmcnt(0)" ::: "memory");
    __builtin_amdgcn_sched_barrier(0);
  }

  __shared__ float zsh[1024];
  __shared__ unsigned hq[2][64];

  if (tid < 64){ hq[0][tid] = 0u; }
  __syncthreads();

  float c_st = 0.f, h_st = 0.f;
  int t0 = dir ? 255 : 0;
  uint2 zw = uint2{0u, 0u};
  if (tid < 256) zw = Zp[(size_t)(b * 256 + t0) * 256 + tid];

  for (int s_ = 0; s_ < 256; ++s_){
    int t = dir ? (255 - s_) : s_;
    int tn = dir ? (t - 1) : (t + 1);
    int cur = s_ & 1, nxt = cur ^ 1;
    // prefetch next step's Z (1 step of latency cover)
    uint2 zw_n = uint2{0u, 0u};
    if (tid < 256 && s_ < 255) zw_n = Zp[(size_t)(b * 256 + tn) * 256 + tid];
    // matvec: both columns share one h-broadcast read
    int aA0 = 0, aA1 = 0, aB0 = 0, aB1 = 0;
    const uint4* hp = (const uint4*)hq[cur];
    #pragma unroll
    for (int i = 0; i < 16; i++){
      uint4 hv = hp[i];
      aA0 = sdot4(uqA[i][0], hv.x, aA0);
      aA1 = sdot4(uqA[i][1], hv.y, aA1);
      aB0 = sdot4(uqB[i][0], hv.x, aB0);
      aB1 = sdot4(uqB[i][1], hv.y, aB1);
      aA0 = sdot4(uqA[i][2], hv.z, aA0);
      aA1 = sdot4(uqA[i][3], hv.w, aA1);
      aB0 = sdot4(uqB[i][2], hv.z, aB0);
      aB1 = sdot4(uqB[i][3], hv.w, aB1);
    }
    zsh[c0] = (float)(aA0 + aA1) * scA;
    zsh[c1] = (float)(aB0 + aB1) * scB;
    __syncthreads();
    if (tid < 256){
      float zi = bf2f(zw.x & 0xffffu) + zsh[tid];
      float zf = bf2f(zw.x >> 16)     + zsh[256 + tid];
      float zg = bf2f(zw.y & 0xffffu) + zsh[512 + tid];
      float zo = bf2f(zw.y >> 16)     + zsh[768 + tid];
      if (t < alen){
        c_st = fsig(zf) * c_st + fsig(zi) * ftanh(zg);
        h_st = fsig(zo) * ftanh(c_st);
      }
      // i8-quantized h for next step
      int ri = __float2int_rn(h_st * 127.f);
      ((char*)hq[nxt])[tid] = (char)ri;
      // bf16 h out (pair-packed u32 stores)
      unsigned hw = f2bf(h_st);
      unsigned other = (unsigned)__shfl_xor((int)hw, 1);
      if (!(tid & 1)){
        unsigned word = hw | (other << 16);
        *(unsigned*)&H[(size_t)(b * 256 + t) * H_ + tid] = word;
      }
    }
    __syncthreads();
    zw = zw_n;
  }
}

// ===== pot = [hf|hb] @ Wd + bd (one wave per row, bf16 h) =====
__global__ __launch_bounds__(256) void k_pot(const ushort* __restrict__ hf16,
        const ushort* __restrict__ hb16, const float* __restrict__ Wd,
        const float* __restrict__ bd, float* __restrict__ out, int* __restrict__ cnt){
  if (blockIdx.x == 0 && threadIdx.x == 0) *cnt = 0;
  int lane = threadIdx.x & 63, wid = threadIdx.x >> 6;
  int m = blockIdx.x * 4 + wid;
  uint2 ua = *(const uint2*)&hf16[(size_t)m * H_ + lane * 4];
  uint2 ub = *(const uint2*)&hb16[(size_t)m * H_ + lane * 4];
  float av[4] = {bf2f(ua.x & 0xFFFFu), bf2f(ua.x >> 16), bf2f(ua.y & 0xFFFFu), bf2f(ua.y >> 16)};
  float bv[4] = {bf2f(ub.x & 0xFFFFu), bf2f(ub.x >> 16), bf2f(ub.y & 0xFFFFu), bf2f(ub.y >> 16)};
  float acc[9];
  #pragma unroll
  for (int l = 0; l < 9; l++) acc[l] = 0.f;
  #pragma unroll
  for (int i = 0; i < 4; i++){
    int r = lane * 4 + i;
    #pragma unroll
    for (int l = 0; l < 9; l++)
      acc[l] += av[i] * Wd[r * 9 + l] + bv[i] * Wd[(H_ + r) * 9 + l];
  }
  #pragma unroll
  for (int off = 32; off; off >>= 1)
    #pragma unroll
    for (int l = 0; l < 9; l++) acc[l] += __shfl_xor(acc[l], off);
  if (lane == 0){
    #pragma unroll
    for (int l = 0; l < 9; l++) out[(size_t)m * 9 + l] = acc[l] + bd[l];
  }
}

// ===== CRF log-likelihood + loss (fused, last-block reduce) =====
__global__ void k_post(const float* __restrict__ out, const int* __restrict__ tags,
                       const float* __restrict__ trans, const int* __restrict__ lens,
                       float* __restrict__ lln, int* cnt, float* __restrict__ loss_out){
  int b = blockIdx.x, lane = threadIdx.x;
  int len = lens[b];
  const float* pot = out + (size_t)b * T_ * 9;
  float up = 0.f, bp = 0.f;
  for (int t = lane; t < T_; t += 64){
    int tg = tags[b * T_ + t];
    if (t < len) up += pot[t * 9 + tg];
    if (t + 1 < len){
      int tg2 = tags[b * T_ + t + 1];
      bp += trans[tg * 9 + tg2];
    }
  }
  for (int off = 32; off; off >>= 1){ up += __shfl_xor(up, off); bp += __shfl_xor(bp, off); }
  float alpha = 0.f;
  if (lane < 9){
    float tr[9];
    #pragma unroll
    for (int i = 0; i < 9; i++) tr[i] = trans[i * 9 + lane];
    alpha = pot[lane];
    for (int t = 1; t < T_; ++t){
      float v[9];
      #pragma unroll
      for (int i = 0; i < 9; i++) v[i] = __shfl(alpha, i) + tr[i];
      float mx = v[0];
      #pragma unroll
      for (int i = 1; i < 9; i++) mx = fmaxf(mx, v[i]);
      float sum = 0.f;
      #pragma unroll
      for (int i = 0; i < 9; i++) sum += __expf(v[i] - mx);
      float an = pot[t * 9 + lane] + mx + __logf(sum);
      if (t < len) alpha = an;
    }
  }
  float mx2 = -3.4e38f;
  for (int i = 0; i < 9; i++){ float a = __shfl(alpha, i); mx2 = fmaxf(mx2, a); }
  float s2 = 0.f;
  for (int i = 0; i < 9; i++){ float a = __shfl(alpha, i); s2 += __expf(a - mx2); }
  float lse = mx2 + __logf(s2);
  __shared__ int lastf;
  if (lane == 0){
    __hip_atomic_store(&lln[b], (up + bp - lse) / (float)len,
                       __ATOMIC_RELAXED, __HIP_MEMORY_SCOPE_AGENT);
    int old = __hip_atomic_fetch_add(cnt, 1, __ATOMIC_ACQ_REL, __HIP_MEMORY_SCOPE_AGENT);
    lastf = (old == 63);
  }
  __syncthreads();
  if (lastf){
    float v = __hip_atomic_load(&lln[lane], __ATOMIC_RELAXED, __HIP_MEMORY_SCOPE_AGENT);
    for (int off = 32; off; off >>= 1) v += __shfl_xor(v, off);
    if (lane == 0) loss_out[0] = -v * (1.f / 64.f);
  }
}

extern "C" void kernel_launch(void* const* d_in, const int* in_sizes, int n_in,
                              void* d_out, int out_size, void* d_ws, size_t ws_size,
                              hipStream_t stream) {
  (void)in_sizes; (void)n_in; (void)out_size; (void)ws_size;
  const int*   inp   = (const int*)  d_in[0];
  const int*   tags  = (const int*)  d_in[1];
  const float* emb   = (const float*)d_in[2];
  const float* Wf    = (const float*)d_in[3];
  const float* Uf    = (const float*)d_in[4];
  const float* bfv   = (const float*)d_in[5];
  const float* Wb    = (const float*)d_in[6];
  const float* Ub    = (const float*)d_in[7];
  const float* bbv   = (const float*)d_in[8];
  const float* Wd    = (const float*)d_in[9];
  const float* bd    = (const float*)d_in[10];
  const float* trans = (const float*)d_in[11];
  float* out = (float*)d_out;

  char* ws = (char*)d_ws;
  unsigned* Uq   = (unsigned*)(ws);                 // 512 KB (col-major [dir][c][kq])
  float*    su   = (float*)   (ws + 524288);        // 8 KB
  ushort*   WT16 = (ushort*)  (ws + 1048576);       // 1 MB
  ushort*   Xbf  = (ushort*)  (ws + 2097152);       // 8 MB
  int*      cnt  = (int*)     (ws + 2097152);       // aliases Xbf (dead by k_pot)
  ushort*   Zpf  = (ushort*)  (ws + 10485760);      // 32 MB packed bf16 [tok][j][g]
  ushort*   Zpb  = (ushort*)  (ws + 44040192);      // 32 MB
  ushort*   hf16 = (ushort*)  (ws + 77594624);      // 8 MB
  ushort*   hb16 = (ushort*)  (ws + 85983232);      // 8 MB
  int*      lens = (int*)     (ws + 94371840);      // 256 B
  float*    lln  = (float*)   (ws + 94372096);      // 256 B

  k_prep<<<6160, 256, 0, stream>>>(inp, emb, Wf, Wb, Uf, Ub, WT16, Uq, su, Xbf,
                                   lens, out + 147456);
  k_gemm<<<dim3(128, 8, 2), 256, 0, stream>>>(Xbf, WT16, bfv, bbv, Zpf, Zpb);
  k_recur9<<<128, 512, 0, stream>>>(Zpf, Zpb, Uq, su, lens, hf16, hb16);
  k_pot<<<4096, 256, 0, stream>>>(hf16, hb16, Wd, bd, out, cnt);
  k_post<<<64, 64, 0, stream>>>(out, tags, trans, lens, lln, cnt, out + 147520);
}